// Round 2
// baseline (8453.493 us; speedup 1.0000x reference)
//
#include <hip/hip_runtime.h>

// SPINN stack-encoder v2: column-owner persistent kernel, fp32.
// 256 WGs x 512 threads (8 waves/CU). Each WG owns 2 output columns (all 4
// tree gates) + 1 tracking gate column. Weights read via wave-uniform s_load
// (no LDS weight tiles); operands read directly from global (L2/L1).
// 2 grid barriers per step; only cross-WG traffic = stack row + tg + th/tc.

constexpr int NB  = 128;
constexpr int LL  = 32;
constexpr int TT  = 63;
constexpr int NWG = 256;
constexpr int NTH = 512;
constexpr int SROWS = 64;

struct Params {
  const float* seq; const int* trans;
  const float* Wx[4];                // i,o,f,u ; Wx[2]==W_o (ref bug kept)
  const float* Ul[4]; const float* Ur[4];
  const float* bias[4];              // b_i, b_o, b_f, b_u
  const float* tWih; const float* tWhh; const float* tbih; const float* tbhh;
  const float* th0; const float* tc0;
  float* stack; float* tg;
  float* thb[2]; float* tcb[2];
  unsigned* cnt; unsigned* bar;
  float* out;
};

__device__ __forceinline__ float sigm(float x) { return 1.0f / (1.0f + __expf(-x)); }
__device__ __forceinline__ float tanh_f(float x) {
  x = fminf(fmaxf(x, -15.0f), 15.0f);
  float e = __expf(2.0f * x);
  return (e - 1.0f) / (e + 1.0f);
}

__device__ __forceinline__ void gsync(unsigned* cnt, unsigned* bar, unsigned gen) {
  __syncthreads();
  if (threadIdx.x == 0) {
    __threadfence();
    unsigned arrived = __hip_atomic_fetch_add(cnt, 1u, __ATOMIC_ACQ_REL,
                                              __HIP_MEMORY_SCOPE_AGENT) + 1u;
    if (arrived == (unsigned)NWG) {
      __hip_atomic_store(cnt, 0u, __ATOMIC_RELAXED, __HIP_MEMORY_SCOPE_AGENT);
      __hip_atomic_store(bar, gen, __ATOMIC_RELEASE, __HIP_MEMORY_SCOPE_AGENT);
    } else {
      while (__hip_atomic_load(bar, __ATOMIC_ACQUIRE, __HIP_MEMORY_SCOPE_AGENT) < gen) {
        __builtin_amdgcn_s_sleep(2);
      }
    }
    __threadfence();
  }
  __syncthreads();
}

__launch_bounds__(NTH)
__global__ void spinn_kernel(Params p) {
  const int w = blockIdx.x;
  const int t = threadIdx.x;

  __shared__ float th2s[NB][65];          // tracking h2, all b (redundant per WG)
  __shared__ float accS[4][NB][10];       // [q][b][8 tree dots + tacc]
  __shared__ float preS[NB][10];          // gate preactivations [b][g*2+n]
  __shared__ float tbsum[256];
  __shared__ unsigned char qstk[NB][64];
  __shared__ short qln[NB];
  __shared__ short bpt[NB];
  __shared__ unsigned char sp1s[NB], sp2s[NB], reds[NB], bufs[NB];
  __shared__ int anyred;

  const int n0 = w * 2;                              // owned tree cols n0,n0+1
  const int b  = t & 127;
  const int q_s = __builtin_amdgcn_readfirstlane(t >> 7);   // wave-uniform 0..3
  const int hoff = (q_s & 1) * 256;                  // K offset within h-region

  // 8 tree weight bases, wave-uniform (g-major: i,o,f,u ; n inner)
  const float* Uq[8];
  #pragma unroll
  for (int g = 0; g < 4; ++g) {
    const float* Um = (q_s < 2) ? p.Ul[g] : p.Ur[g];
    Uq[g * 2 + 0] = Um + (size_t)(n0 + 0) * 512 + hoff;
    Uq[g * 2 + 1] = Um + (size_t)(n0 + 1) * 512 + hoff;
  }
  const float* wtMid = p.tWih + (size_t)w * 1536 + 512 + q_s * 256;

  // ---- prologue
  if (t < 256) tbsum[t] = p.tbih[t] + p.tbhh[t];
  {
    int i = w * NTH + t;                 // exactly covers 128*1024 = 131072
    p.stack[(size_t)(i >> 10) * (SROWS * 1024) + (i & 1023)] = 0.0f;
  }
  if (w == 0) {
    for (int i = t; i < NB * 64; i += NTH) { p.thb[0][i] = p.th0[i]; p.tcb[0][i] = p.tc0[i]; }
  }
  if (t < NB) { qln[t] = 0; bpt[t] = 0; }
  __syncthreads();
  unsigned gen = 0;
  gsync(p.cnt, p.bar, ++gen);

  for (int step = 1; step <= TT; ++step) {
    const int cur = (step - 1) & 1, nxt = step & 1;

    // ---- schedule sim (redundant per WG, LDS-local)
    if (t < NB) {
      int bb = t;
      int mask = p.trans[bb * TT + (step - 1)];
      int qn = qln[bb];
      int s1 = (qn >= 1) ? qstk[bb][qn - 1] : 0;
      int s2 = (qn >= 2) ? qstk[bb][qn - 2] : 0;
      int rd = (mask == 1);
      sp1s[bb] = (unsigned char)s1;
      sp2s[bb] = (unsigned char)s2;
      reds[bb] = (unsigned char)rd;
      int bp = bpt[bb];
      bufs[bb] = (unsigned char)((bp < LL) ? bp : LL);
      int qn2 = rd ? (qn - 2) : qn;
      qstk[bb][qn2] = (unsigned char)step;
      qln[bb] = (short)(qn2 + 1);
      bpt[bb] = (short)(bp + (rd ? 0 : 1));
    }
    __syncthreads();
    if (t == 0) { int a = 0; for (int b2 = 0; b2 < NB; ++b2) a |= reds[b2]; anyred = a; }
    __syncthreads();

    // ================= SEG 1: tree U-pre (K-split by q) + tracking col =====
    float acc[8];
    #pragma unroll
    for (int d = 0; d < 8; ++d) acc[d] = 0.0f;
    float tacc = 0.0f;

    {
      const int sp = (q_s < 2) ? sp1s[b] : sp2s[b];
      const float* op = p.stack + ((size_t)b * SROWS + sp) * 1024 + hoff;
      if (anyred) {
        #pragma unroll 2
        for (int ks = 0; ks < 256; ks += 4) {
          float4 v = *(const float4*)(op + ks);
          float4 tw = *(const float4*)(wtMid + ks);          // s_load (uniform)
          tacc += v.x * tw.x + v.y * tw.y + v.z * tw.z + v.w * tw.w;
          #pragma unroll
          for (int d = 0; d < 8; ++d) {
            float4 wv = *(const float4*)(Uq[d] + ks);        // s_load (uniform)
            acc[d] += v.x * wv.x + v.y * wv.y + v.z * wv.z + v.w * wv.w;
          }
        }
      } else {
        #pragma unroll 4
        for (int ks = 0; ks < 256; ks += 4) {
          float4 v = *(const float4*)(op + ks);
          float4 tw = *(const float4*)(wtMid + ks);
          tacc += v.x * tw.x + v.y * tw.y + v.z * tw.z + v.w * tw.w;
        }
      }
    }
    // tracking extra-K: buf_h [0,512) and th [1536,1600), split 144/q
    {
      const int e0 = q_s * 144;
      const int bi = bufs[b];
      #pragma unroll 2
      for (int e4 = 0; e4 < 144; e4 += 4) {
        int e = e0 + e4;                                     // scalar
        float4 v, wv;
        if (e < 512) {
          if (bi < LL) v = *(const float4*)(p.seq + ((size_t)b * LL + bi) * 1024 + e);
          else v = make_float4(0.f, 0.f, 0.f, 0.f);
          wv = *(const float4*)(p.tWih + (size_t)w * 1536 + e);
        } else {
          v  = *(const float4*)(p.thb[cur] + (size_t)b * 64 + (e - 512));
          wv = *(const float4*)(p.tWhh + (size_t)w * 64 + (e - 512));
        }
        tacc += v.x * wv.x + v.y * wv.y + v.z * wv.z + v.w * wv.w;
      }
    }
    #pragma unroll
    for (int d = 0; d < 8; ++d) accS[q_s][b][d] = acc[d];
    accS[q_s][b][8] = tacc;
    __syncthreads();
    if (t < NB) {
      float tv = accS[0][t][8] + accS[1][t][8] + accS[2][t][8] + accS[3][t][8];
      p.tg[(size_t)w * NB + t] = tv;                         // [c][b], coalesced
    }

    gsync(p.cnt, p.bar, ++gen);

    // ================= SEG 2: th2 + x@W + tree elementwise + stack write ===
    // prefetch c_l/c_r/buf for the final elementwise (t<256)
    float clv = 0.f, crv = 0.f, bhv = 0.f, bcv = 0.f;
    const int bF = t & 127, nF = (t >> 7) & 1;
    if (t < 256) {
      clv = p.stack[((size_t)bF * SROWS + sp1s[bF]) * 1024 + 512 + n0 + nF];
      crv = p.stack[((size_t)bF * SROWS + sp2s[bF]) * 1024 + 512 + n0 + nF];
      int bi = bufs[bF];
      if (bi < LL) {
        bhv = p.seq[((size_t)bF * LL + bi) * 1024 + n0 + nF];
        bcv = p.seq[((size_t)bF * LL + bi) * 1024 + 512 + n0 + nF];
      }
    }
    // th2 for all b, redundant per WG (tg reads coalesced over lanes=b)
    {
      const int bb = t & 127, jq = t >> 7;                   // jq wave-uniform
      const float* tcrow = p.tcb[cur] + (size_t)bb * 64;
      for (int jj = 0; jj < 16; ++jj) {
        int j = jq * 16 + jj;
        float gi = p.tg[(size_t)(j      ) * NB + bb] + tbsum[j];
        float gf = p.tg[(size_t)(64 + j ) * NB + bb] + tbsum[64 + j];
        float gg = p.tg[(size_t)(128 + j) * NB + bb] + tbsum[128 + j];
        float go = p.tg[(size_t)(192 + j) * NB + bb] + tbsum[192 + j];
        float c2 = sigm(gf) * tcrow[j] + sigm(gi) * tanh_f(gg);
        float h2 = sigm(go) * tanh_f(c2);
        th2s[bb][j] = h2;
        if (w == bb) {                                       // unique writer per b
          p.thb[nxt][(size_t)bb * 64 + j] = h2;
          p.tcb[nxt][(size_t)bb * 64 + j] = c2;
        }
      }
    }
    __syncthreads();
    if (anyred) {
      const int b2 = t & 127;
      const int sel = __builtin_amdgcn_readfirstlane(t >> 7);  // gate 0..3
      const float* W0 = p.Wx[sel] + (size_t)(n0    ) * 64;
      const float* W1 = p.Wx[sel] + (size_t)(n0 + 1) * 64;
      float x0 = 0.f, x1 = 0.f;
      #pragma unroll 4
      for (int j4 = 0; j4 < 64; j4 += 4) {
        float4 wa = *(const float4*)(W0 + j4);               // s_load
        float4 wb = *(const float4*)(W1 + j4);               // s_load
        float v0 = th2s[b2][j4], v1 = th2s[b2][j4 + 1];
        float v2 = th2s[b2][j4 + 2], v3 = th2s[b2][j4 + 3];
        x0 += v0 * wa.x + v1 * wa.y + v2 * wa.z + v3 * wa.w;
        x1 += v0 * wb.x + v1 * wb.y + v2 * wb.z + v3 * wb.w;
      }
      float bi0 = p.bias[sel][n0], bi1 = p.bias[sel][n0 + 1];
      preS[b2][sel * 2 + 0] = accS[0][b2][sel * 2] + accS[1][b2][sel * 2]
                            + accS[2][b2][sel * 2] + accS[3][b2][sel * 2] + x0 + bi0;
      preS[b2][sel * 2 + 1] = accS[0][b2][sel * 2 + 1] + accS[1][b2][sel * 2 + 1]
                            + accS[2][b2][sel * 2 + 1] + accS[3][b2][sel * 2 + 1] + x1 + bi1;
    }
    __syncthreads();
    if (t < 256) {
      float h, c;
      if (reds[bF]) {
        float iv = sigm(preS[bF][0 + nF]);
        float ov = sigm(preS[bF][2 + nF]);
        float fv = sigm(preS[bF][4 + nF]);
        float uv = tanh_f(preS[bF][6 + nF]);
        c = iv * uv + fv * (clv + crv);
        h = ov * tanh_f(c);
      } else { h = bhv; c = bcv; }
      float* sr = p.stack + ((size_t)bF * SROWS + step) * 1024 + n0 + nF;
      sr[0] = h;
      sr[512] = c;
      if (step == TT) p.out[(size_t)bF * 512 + n0 + nF] = h;
    }
    gsync(p.cnt, p.bar, ++gen);
  }
}

extern "C" void kernel_launch(void* const* d_in, const int* in_sizes, int n_in,
                              void* d_out, int out_size, void* d_ws, size_t ws_size,
                              hipStream_t stream) {
  Params p;
  p.seq   = (const float*)d_in[0];
  p.trans = (const int*)d_in[1];
  p.Wx[0] = (const float*)d_in[2];   // W_i
  p.Wx[1] = (const float*)d_in[4];   // W_o
  p.Wx[2] = (const float*)d_in[4];   // W_o  (ref bug: f-gate uses W_o)
  p.Wx[3] = (const float*)d_in[5];   // W_u
  p.Ul[0] = (const float*)d_in[6];  p.Ur[0] = (const float*)d_in[7];    // i
  p.Ul[1] = (const float*)d_in[10]; p.Ur[1] = (const float*)d_in[11];   // o
  p.Ul[2] = (const float*)d_in[8];  p.Ur[2] = (const float*)d_in[9];    // f
  p.Ul[3] = (const float*)d_in[12]; p.Ur[3] = (const float*)d_in[13];   // u
  p.bias[0] = (const float*)d_in[14];  // b_i
  p.bias[1] = (const float*)d_in[16];  // b_o
  p.bias[2] = (const float*)d_in[15];  // b_f
  p.bias[3] = (const float*)d_in[17];  // b_u
  p.tWih = (const float*)d_in[18];
  p.tWhh = (const float*)d_in[19];
  p.tbih = (const float*)d_in[20];
  p.tbhh = (const float*)d_in[21];
  p.th0  = (const float*)d_in[22];
  p.tc0  = (const float*)d_in[23];

  float* ws = (float*)d_ws;
  size_t off = 0;
  p.stack  = ws + off; off += (size_t)NB * SROWS * 1024;  // 32 MB
  p.tg     = ws + off; off += (size_t)256 * NB;           // 128 KB
  p.thb[0] = ws + off; off += NB * 64;
  p.thb[1] = ws + off; off += NB * 64;
  p.tcb[0] = ws + off; off += NB * 64;
  p.tcb[1] = ws + off; off += NB * 64;
  unsigned* barmem = (unsigned*)(ws + off); off += 16;
  if (off * sizeof(float) > ws_size) return;
  p.cnt = barmem;
  p.bar = barmem + 1;
  p.out = (float*)d_out;

  hipMemsetAsync(barmem, 0, 2 * sizeof(unsigned), stream);

  void* args[] = { &p };
  hipError_t e = hipLaunchCooperativeKernel((void*)spinn_kernel, dim3(NWG), dim3(NTH),
                                            args, 0, stream);
  if (e != hipSuccess) {
    (void)hipGetLastError();
    spinn_kernel<<<dim3(NWG), dim3(NTH), 0, stream>>>(p);
  }
}

// Round 3
// 5060.402 us; speedup vs baseline: 1.6705x; 1.6705x over previous
//
#include <hip/hip_runtime.h>

// SPINN stack-encoder v3: v2 column-owner structure + fixed grid barrier.
// Barrier: hierarchical monotonic counters (8 sub-lines x 32 WGs + root),
// RELAXED atomics only, single device fence each side (no per-poll
// cache invalidation -- v2's acquire-spin was nuking L1/L2 chip-wide).
// Tracking state th/tc now lives in per-WG LDS (redundant compute from tg).

constexpr int NB  = 128;
constexpr int LL  = 32;
constexpr int TT  = 63;
constexpr int NWG = 256;
constexpr int NTH = 512;
constexpr int SROWS = 64;

struct Params {
  const float* seq; const int* trans;
  const float* Wx[4];                // i,o,f,u ; Wx[2]==W_o (ref bug kept)
  const float* Ul[4]; const float* Ur[4];
  const float* bias[4];              // b_i, b_o, b_f, b_u
  const float* tWih; const float* tWhh; const float* tbih; const float* tbhh;
  const float* th0; const float* tc0;
  float* stack; float* tg;
  unsigned* bm;                      // barrier memory (>=512 u32, zeroed per call)
  float* out;
};

__device__ __forceinline__ float sigm(float x) { return 1.0f / (1.0f + __expf(-x)); }
__device__ __forceinline__ float tanh_f(float x) {
  x = fminf(fmaxf(x, -15.0f), 15.0f);
  float e = __expf(2.0f * x);
  return (e - 1.0f) / (e + 1.0f);
}

// Monotonic hierarchical grid barrier. Counters never reset (a==gen*32,
// r==gen*8) so there is no reset/rearrival race with relaxed atomics.
// Data visibility: one release fence before arrival, one acquire after.
__device__ __forceinline__ void gsync(unsigned* bm, unsigned gen, int w) {
  __syncthreads();
  if (threadIdx.x == 0) {
    __threadfence();                                   // release (wb)
    unsigned* c    = bm + (w & 7) * 32;                // 128B-separated lines
    unsigned* root = bm + 320;
    unsigned* bar  = bm + 352;
    unsigned a = __hip_atomic_fetch_add(c, 1u, __ATOMIC_RELAXED,
                                        __HIP_MEMORY_SCOPE_AGENT) + 1u;
    if (a == gen * 32u) {
      unsigned r = __hip_atomic_fetch_add(root, 1u, __ATOMIC_RELAXED,
                                          __HIP_MEMORY_SCOPE_AGENT) + 1u;
      if (r == gen * 8u) {
        __hip_atomic_store(bar, gen, __ATOMIC_RELAXED, __HIP_MEMORY_SCOPE_AGENT);
      }
    }
    while (__hip_atomic_load(bar, __ATOMIC_RELAXED, __HIP_MEMORY_SCOPE_AGENT) < gen) {
      __builtin_amdgcn_s_sleep(1);
    }
    __threadfence();                                   // acquire (inv, once)
  }
  __syncthreads();
}

__launch_bounds__(NTH)
__global__ void spinn_kernel(Params p) {
  const int w = blockIdx.x;
  const int t = threadIdx.x;

  __shared__ float th2s[NB][65];          // tracking h state (WG-local, all b)
  __shared__ float tc2s[NB][65];          // tracking c state (WG-local, all b)
  __shared__ float accS[4][NB][10];       // [q][b][8 tree dots + tacc]
  __shared__ float preS[NB][10];          // gate preactivations [b][g*2+n]
  __shared__ float tbsum[256];
  __shared__ unsigned char qstk[NB][64];
  __shared__ short qln[NB];
  __shared__ short bpt[NB];
  __shared__ unsigned char sp1s[NB], sp2s[NB], reds[NB], bufs[NB];
  __shared__ int anyred;

  const int n0 = w * 2;                              // owned tree cols n0,n0+1
  const int b  = t & 127;
  const int q_s = __builtin_amdgcn_readfirstlane(t >> 7);   // wave-uniform 0..3
  const int hoff = (q_s & 1) * 256;                  // K offset within h-region

  // 8 tree weight bases, wave-uniform (g-major: i,o,f,u ; n inner)
  const float* Uq[8];
  #pragma unroll
  for (int g = 0; g < 4; ++g) {
    const float* Um = (q_s < 2) ? p.Ul[g] : p.Ur[g];
    Uq[g * 2 + 0] = Um + (size_t)(n0 + 0) * 512 + hoff;
    Uq[g * 2 + 1] = Um + (size_t)(n0 + 1) * 512 + hoff;
  }
  const float* wtMid = p.tWih + (size_t)w * 1536 + 512 + q_s * 256;

  // ---- prologue
  if (t < 256) tbsum[t] = p.tbih[t] + p.tbhh[t];
  for (int i = t; i < NB * 64; i += NTH) {
    th2s[i >> 6][i & 63] = p.th0[i];
    tc2s[i >> 6][i & 63] = p.tc0[i];
  }
  {
    int i = w * NTH + t;                 // exactly covers 128*1024 (stack row 0)
    p.stack[(size_t)(i >> 10) * (SROWS * 1024) + (i & 1023)] = 0.0f;
  }
  if (t < NB) { qln[t] = 0; bpt[t] = 0; }
  unsigned gen = 0;
  gsync(p.bm, ++gen, w);

  for (int step = 1; step <= TT; ++step) {
    // ---- schedule sim (redundant per WG, LDS-local)
    if (t < NB) {
      int bb = t;
      int mask = p.trans[bb * TT + (step - 1)];
      int qn = qln[bb];
      int s1 = (qn >= 1) ? qstk[bb][qn - 1] : 0;
      int s2 = (qn >= 2) ? qstk[bb][qn - 2] : 0;
      int rd = (mask == 1);
      sp1s[bb] = (unsigned char)s1;
      sp2s[bb] = (unsigned char)s2;
      reds[bb] = (unsigned char)rd;
      int bp = bpt[bb];
      bufs[bb] = (unsigned char)((bp < LL) ? bp : LL);
      int qn2 = rd ? (qn - 2) : qn;
      qstk[bb][qn2] = (unsigned char)step;
      qln[bb] = (short)(qn2 + 1);
      bpt[bb] = (short)(bp + (rd ? 0 : 1));
    }
    __syncthreads();
    if (t == 0) { int a = 0; for (int b2 = 0; b2 < NB; ++b2) a |= reds[b2]; anyred = a; }
    __syncthreads();

    // ================= SEG 1: tree U-pre (K-split by q) + tracking col =====
    float acc[8];
    #pragma unroll
    for (int d = 0; d < 8; ++d) acc[d] = 0.0f;
    float tacc = 0.0f;

    {
      const int sp = (q_s < 2) ? sp1s[b] : sp2s[b];
      const float* op = p.stack + ((size_t)b * SROWS + sp) * 1024 + hoff;
      if (anyred) {
        #pragma unroll 4
        for (int ks = 0; ks < 256; ks += 4) {
          float4 v = *(const float4*)(op + ks);
          float4 tw = *(const float4*)(wtMid + ks);          // uniform -> s_load
          tacc += v.x * tw.x + v.y * tw.y + v.z * tw.z + v.w * tw.w;
          #pragma unroll
          for (int d = 0; d < 8; ++d) {
            float4 wv = *(const float4*)(Uq[d] + ks);        // uniform -> s_load
            acc[d] += v.x * wv.x + v.y * wv.y + v.z * wv.z + v.w * wv.w;
          }
        }
      } else {
        #pragma unroll 8
        for (int ks = 0; ks < 256; ks += 4) {
          float4 v = *(const float4*)(op + ks);
          float4 tw = *(const float4*)(wtMid + ks);
          tacc += v.x * tw.x + v.y * tw.y + v.z * tw.z + v.w * tw.w;
        }
      }
    }
    // tracking extra-K: buf_h [0,512) from seq, th [1536,1600) from LDS state
    {
      const int e0 = q_s * 144;
      const int bi = bufs[b];
      #pragma unroll 4
      for (int e4 = 0; e4 < 144; e4 += 4) {
        int e = e0 + e4;
        if (e < 512) {
          float4 v;
          if (bi < LL) v = *(const float4*)(p.seq + ((size_t)b * LL + bi) * 1024 + e);
          else v = make_float4(0.f, 0.f, 0.f, 0.f);
          float4 wv = *(const float4*)(p.tWih + (size_t)w * 1536 + e);
          tacc += v.x * wv.x + v.y * wv.y + v.z * wv.z + v.w * wv.w;
        } else {
          int j = e - 512;
          float4 wv = *(const float4*)(p.tWhh + (size_t)w * 64 + j);
          tacc += th2s[b][j]     * wv.x + th2s[b][j + 1] * wv.y
                + th2s[b][j + 2] * wv.z + th2s[b][j + 3] * wv.w;
        }
      }
    }
    #pragma unroll
    for (int d = 0; d < 8; ++d) accS[q_s][b][d] = acc[d];
    accS[q_s][b][8] = tacc;
    __syncthreads();
    if (t < NB) {
      float tv = accS[0][t][8] + accS[1][t][8] + accS[2][t][8] + accS[3][t][8];
      p.tg[(size_t)w * NB + t] = tv;                         // [c][b], coalesced
    }

    gsync(p.bm, ++gen, w);

    // ================= SEG 2: th2 + x@W + tree elementwise + stack write ===
    // prefetch c_l/c_r/buf for the final elementwise (t<256)
    float clv = 0.f, crv = 0.f, bhv = 0.f, bcv = 0.f;
    const int bF = t & 127, nF = (t >> 7) & 1;
    if (t < 256) {
      clv = p.stack[((size_t)bF * SROWS + sp1s[bF]) * 1024 + 512 + n0 + nF];
      crv = p.stack[((size_t)bF * SROWS + sp2s[bF]) * 1024 + 512 + n0 + nF];
      int bi = bufs[bF];
      if (bi < LL) {
        bhv = p.seq[((size_t)bF * LL + bi) * 1024 + n0 + nF];
        bcv = p.seq[((size_t)bF * LL + bi) * 1024 + 512 + n0 + nF];
      }
    }
    // tracking state update for ALL b, redundant per WG (LDS-resident state)
    {
      const int bb = t & 127, jq = t >> 7;                   // jq wave-uniform
      #pragma unroll 4
      for (int jj = 0; jj < 16; ++jj) {
        int j = jq * 16 + jj;
        float gi = p.tg[(size_t)(j      ) * NB + bb] + tbsum[j];
        float gf = p.tg[(size_t)(64 + j ) * NB + bb] + tbsum[64 + j];
        float gg = p.tg[(size_t)(128 + j) * NB + bb] + tbsum[128 + j];
        float go = p.tg[(size_t)(192 + j) * NB + bb] + tbsum[192 + j];
        float c2 = sigm(gf) * tc2s[bb][j] + sigm(gi) * tanh_f(gg);
        float h2 = sigm(go) * tanh_f(c2);
        th2s[bb][j] = h2;
        tc2s[bb][j] = c2;
      }
    }
    __syncthreads();
    if (anyred) {
      const int b2 = t & 127;
      const int sel = __builtin_amdgcn_readfirstlane(t >> 7);  // gate 0..3
      const float* W0 = p.Wx[sel] + (size_t)(n0    ) * 64;
      const float* W1 = p.Wx[sel] + (size_t)(n0 + 1) * 64;
      float x0 = 0.f, x1 = 0.f;
      #pragma unroll 4
      for (int j4 = 0; j4 < 64; j4 += 4) {
        float4 wa = *(const float4*)(W0 + j4);               // uniform -> s_load
        float4 wb = *(const float4*)(W1 + j4);               // uniform -> s_load
        float v0 = th2s[b2][j4], v1 = th2s[b2][j4 + 1];
        float v2 = th2s[b2][j4 + 2], v3 = th2s[b2][j4 + 3];
        x0 += v0 * wa.x + v1 * wa.y + v2 * wa.z + v3 * wa.w;
        x1 += v0 * wb.x + v1 * wb.y + v2 * wb.z + v3 * wb.w;
      }
      float bi0 = p.bias[sel][n0], bi1 = p.bias[sel][n0 + 1];
      preS[b2][sel * 2 + 0] = accS[0][b2][sel * 2] + accS[1][b2][sel * 2]
                            + accS[2][b2][sel * 2] + accS[3][b2][sel * 2] + x0 + bi0;
      preS[b2][sel * 2 + 1] = accS[0][b2][sel * 2 + 1] + accS[1][b2][sel * 2 + 1]
                            + accS[2][b2][sel * 2 + 1] + accS[3][b2][sel * 2 + 1] + x1 + bi1;
    }
    __syncthreads();
    if (t < 256) {
      float h, c;
      if (reds[bF]) {
        float iv = sigm(preS[bF][0 + nF]);
        float ov = sigm(preS[bF][2 + nF]);
        float fv = sigm(preS[bF][4 + nF]);
        float uv = tanh_f(preS[bF][6 + nF]);
        c = iv * uv + fv * (clv + crv);
        h = ov * tanh_f(c);
      } else { h = bhv; c = bcv; }
      float* sr = p.stack + ((size_t)bF * SROWS + step) * 1024 + n0 + nF;
      sr[0] = h;
      sr[512] = c;
      if (step == TT) p.out[(size_t)bF * 512 + n0 + nF] = h;
    }
    gsync(p.bm, ++gen, w);
  }
}

extern "C" void kernel_launch(void* const* d_in, const int* in_sizes, int n_in,
                              void* d_out, int out_size, void* d_ws, size_t ws_size,
                              hipStream_t stream) {
  Params p;
  p.seq   = (const float*)d_in[0];
  p.trans = (const int*)d_in[1];
  p.Wx[0] = (const float*)d_in[2];   // W_i
  p.Wx[1] = (const float*)d_in[4];   // W_o
  p.Wx[2] = (const float*)d_in[4];   // W_o  (ref bug: f-gate uses W_o)
  p.Wx[3] = (const float*)d_in[5];   // W_u
  p.Ul[0] = (const float*)d_in[6];  p.Ur[0] = (const float*)d_in[7];    // i
  p.Ul[1] = (const float*)d_in[10]; p.Ur[1] = (const float*)d_in[11];   // o
  p.Ul[2] = (const float*)d_in[8];  p.Ur[2] = (const float*)d_in[9];    // f
  p.Ul[3] = (const float*)d_in[12]; p.Ur[3] = (const float*)d_in[13];   // u
  p.bias[0] = (const float*)d_in[14];  // b_i
  p.bias[1] = (const float*)d_in[16];  // b_o
  p.bias[2] = (const float*)d_in[15];  // b_f
  p.bias[3] = (const float*)d_in[17];  // b_u
  p.tWih = (const float*)d_in[18];
  p.tWhh = (const float*)d_in[19];
  p.tbih = (const float*)d_in[20];
  p.tbhh = (const float*)d_in[21];
  p.th0  = (const float*)d_in[22];
  p.tc0  = (const float*)d_in[23];

  float* ws = (float*)d_ws;
  size_t off = 0;
  p.stack = ws + off; off += (size_t)NB * SROWS * 1024;  // 32 MB
  p.tg    = ws + off; off += (size_t)256 * NB;           // 128 KB
  unsigned* barmem = (unsigned*)(ws + off); off += 512;
  if (off * sizeof(float) > ws_size) return;
  p.bm  = barmem;
  p.out = (float*)d_out;

  // barrier counters must start at 0 every call (monotonic within a call)
  hipMemsetAsync(barmem, 0, 512 * sizeof(unsigned), stream);

  void* args[] = { &p };
  hipError_t e = hipLaunchCooperativeKernel((void*)spinn_kernel, dim3(NWG), dim3(NTH),
                                            args, 0, stream);
  if (e != hipSuccess) {
    (void)hipGetLastError();
    spinn_kernel<<<dim3(NWG), dim3(NTH), 0, stream>>>(p);
  }
}

// Round 4
// 4732.750 us; speedup vs baseline: 1.7862x; 1.0692x over previous
//
#include <hip/hip_runtime.h>

// SPINN stack-encoder v4: all weights LDS-resident (fence-immune), operands
// staged global->LDS in 64-K chunks with register prefetch, 2col x 4b
// register tiles, tc-state in registers. 2 grid barriers/step (monotonic
// relaxed hierarchical barrier from v3).

constexpr int NB  = 128;
constexpr int LL  = 32;
constexpr int TT  = 63;
constexpr int NWG = 256;
constexpr int NTH = 512;
constexpr int SROWS = 64;

struct Params {
  const float* seq; const int* trans;
  const float* Wx[4];                // i,o,f,u ; Wx[2]==W_o (ref bug kept)
  const float* Ul[4]; const float* Ur[4];
  const float* bias[4];              // b_i, b_o, b_f, b_u
  const float* tWih; const float* tWhh; const float* tbih; const float* tbhh;
  const float* th0; const float* tc0;
  float* stack; float* tg;
  unsigned* bm;
  float* out;
};

__device__ __forceinline__ float sigm(float x) { return 1.0f / (1.0f + __expf(-x)); }
__device__ __forceinline__ float tanh_f(float x) {
  x = fminf(fmaxf(x, -15.0f), 15.0f);
  float e = __expf(2.0f * x);
  return (e - 1.0f) / (e + 1.0f);
}

// Monotonic hierarchical grid barrier (relaxed atomics, one fence each side).
__device__ __forceinline__ void gsync(unsigned* bm, unsigned gen, int w) {
  __syncthreads();
  if (threadIdx.x == 0) {
    __threadfence();                                   // release
    unsigned* c    = bm + (w & 7) * 32;
    unsigned* root = bm + 320;
    unsigned* bar  = bm + 352;
    unsigned a = __hip_atomic_fetch_add(c, 1u, __ATOMIC_RELAXED,
                                        __HIP_MEMORY_SCOPE_AGENT) + 1u;
    if (a == gen * 32u) {
      unsigned r = __hip_atomic_fetch_add(root, 1u, __ATOMIC_RELAXED,
                                          __HIP_MEMORY_SCOPE_AGENT) + 1u;
      if (r == gen * 8u) {
        __hip_atomic_store(bar, gen, __ATOMIC_RELAXED, __HIP_MEMORY_SCOPE_AGENT);
      }
    }
    while (__hip_atomic_load(bar, __ATOMIC_RELAXED, __HIP_MEMORY_SCOPE_AGENT) < gen) {
      __builtin_amdgcn_s_sleep(1);
    }
    __threadfence();                                   // acquire
  }
  __syncthreads();
}

__launch_bounds__(NTH)
__global__ void spinn_kernel(Params p) {
  const int w = blockIdx.x;
  const int t = threadIdx.x;

  __shared__ float wTree[8][1024];   // rows g*2+nc; k<512 = Ul, k>=512 = Ur
  __shared__ float wTrk[1600];       // tracking col w: [0,512)buf [512,1024)sp1 [1024,1536)sp2 [1536,1600)th
  __shared__ float wX[8][64];
  __shared__ float tbsum[256];
  __shared__ float biasS[8];
  __shared__ float opS[128][68];     // operand chunk [b][64k], pad->stride 68
  __shared__ float th2s[128][68];    // tracking h state, all b
  __shared__ float accS[4][8][128];  // [q][col][b] tree partials
  __shared__ float accT[16][128];    // tracking partials
  __shared__ float preS[128][9];
  __shared__ unsigned char qstk[128][64];
  __shared__ short qln[128];
  __shared__ short bpt[128];
  __shared__ unsigned char sp1s[128], sp2s[128], reds[128], bufs[128];
  __shared__ int anyred;

  const int n0 = w * 2;                                     // owned h-cols
  const int q  = __builtin_amdgcn_readfirstlane(t >> 7);    // 0..3 (2-wave uniform)
  const int cp = (t >> 5) & 3;
  const int bg = t & 31;
  const int bb = t & 127;

  // ---- prologue: weights -> LDS (fetched exactly once; LDS survives fences)
  for (int i = t; i < 2048; i += NTH) {          // wTree: 8 x 256 float4
    int r = i >> 8, kf = i & 255;
    int g = r >> 1, nc = r & 1;
    int k = kf * 4;
    float4 v;
    if (k < 512) v = *(const float4*)(p.Ul[g] + (size_t)(n0 + nc) * 512 + k);
    else         v = *(const float4*)(p.Ur[g] + (size_t)(n0 + nc) * 512 + (k - 512));
    *(float4*)&wTree[r][k] = v;
  }
  for (int i = t; i < 400; i += NTH) {           // wTrk: 400 float4
    int k = i * 4;
    float4 v;
    if (k < 1536) v = *(const float4*)(p.tWih + (size_t)w * 1536 + k);
    else          v = *(const float4*)(p.tWhh + (size_t)w * 64 + (k - 1536));
    *(float4*)&wTrk[k] = v;
  }
  for (int i = t; i < 128; i += NTH) {           // wX: 8 x 16 float4
    int r = i >> 4, jf = i & 15;
    int g = r >> 1, nc = r & 1;
    *(float4*)&wX[r][jf * 4] = *(const float4*)(p.Wx[g] + (size_t)(n0 + nc) * 64 + jf * 4);
  }
  if (t < 256) tbsum[t] = p.tbih[t] + p.tbhh[t];
  if (t < 8) biasS[t] = p.bias[t >> 1][n0 + (t & 1)];
  for (int i = t; i < 8192; i += NTH) th2s[i >> 6][i & 63] = p.th0[i];
  float tcr[16];                                  // tc state in regs: (bb, q)
  #pragma unroll
  for (int jj = 0; jj < 16; ++jj) tcr[jj] = p.tc0[bb * 64 + q * 16 + jj];
  { int i = w * NTH + t;                          // zero stack row 0
    p.stack[(size_t)(i >> 10) * (SROWS * 1024) + (i & 1023)] = 0.0f; }
  if (t < NB) { qln[t] = 0; bpt[t] = 0; }
  unsigned gen = 0;
  gsync(p.bm, ++gen, w);

  for (int step = 1; step <= TT; ++step) {
    // ---- schedule sim (redundant per WG)
    if (t < NB) {
      int b2 = t;
      int mask = p.trans[b2 * TT + (step - 1)];
      int qn = qln[b2];
      int s1 = (qn >= 1) ? qstk[b2][qn - 1] : 0;
      int s2 = (qn >= 2) ? qstk[b2][qn - 2] : 0;
      int rd = (mask == 1);
      sp1s[b2] = (unsigned char)s1;
      sp2s[b2] = (unsigned char)s2;
      reds[b2] = (unsigned char)rd;
      int bp = bpt[b2];
      bufs[b2] = (unsigned char)((bp < LL) ? bp : LL);
      int qn2 = rd ? (qn - 2) : qn;
      qstk[b2][qn2] = (unsigned char)step;
      qln[b2] = (short)(qn2 + 1);
      bpt[b2] = (short)(bp + (rd ? 0 : 1));
    }
    __syncthreads();
    if (t == 0) { int a = 0; for (int b2 = 0; b2 < NB; ++b2) a |= reds[b2]; anyred = a; }
    __syncthreads();

    // ================= SEG 1 =================
    if (anyred) {
      // staged chunk loop: 24 chunks of 64 K (sp1 h, sp2 h, buf h)
      float acc[2][4];
      #pragma unroll
      for (int ci = 0; ci < 2; ++ci)
        #pragma unroll
        for (int bi = 0; bi < 4; ++bi) acc[ci][bi] = 0.0f;
      float tacc[4] = {0.f, 0.f, 0.f, 0.f};

      const int sf4 = t & 15, srow0 = t >> 4;
      float4 pf[4];
      auto issue = [&](int c) {
        #pragma unroll
        for (int rr = 0; rr < 4; ++rr) {
          int row = srow0 + rr * 32;
          const float* src = nullptr;
          if (c < 8)       src = p.stack + ((size_t)row * SROWS + sp1s[row]) * 1024 + c * 64 + sf4 * 4;
          else if (c < 16) src = p.stack + ((size_t)row * SROWS + sp2s[row]) * 1024 + (c - 8) * 64 + sf4 * 4;
          else { int bx = bufs[row];
                 if (bx < LL) src = p.seq + ((size_t)row * LL + bx) * 1024 + (c - 16) * 64 + sf4 * 4; }
          pf[rr] = src ? *(const float4*)src : make_float4(0.f, 0.f, 0.f, 0.f);
        }
      };
      issue(0);
      for (int c = 0; c < 24; ++c) {
        __syncthreads();
        #pragma unroll
        for (int rr = 0; rr < 4; ++rr) *(float4*)&opS[srow0 + rr * 32][sf4 * 4] = pf[rr];
        __syncthreads();
        if (c + 1 < 24) issue(c + 1);
        const int kW = c * 64;
        const int twoff = (c < 16) ? (512 + c * 64) : ((c - 16) * 64);
        #pragma unroll
        for (int k4 = 0; k4 < 4; ++k4) {
          const int kk = q * 16 + k4 * 4;
          float4 o0 = *(const float4*)&opS[bg     ][kk];
          float4 o1 = *(const float4*)&opS[bg + 32][kk];
          float4 o2 = *(const float4*)&opS[bg + 64][kk];
          float4 o3 = *(const float4*)&opS[bg + 96][kk];
          if (c < 16) {
            float4 a0 = *(const float4*)&wTree[cp * 2    ][kW + kk];
            float4 a1 = *(const float4*)&wTree[cp * 2 + 1][kW + kk];
            acc[0][0] += a0.x*o0.x + a0.y*o0.y + a0.z*o0.z + a0.w*o0.w;
            acc[0][1] += a0.x*o1.x + a0.y*o1.y + a0.z*o1.z + a0.w*o1.w;
            acc[0][2] += a0.x*o2.x + a0.y*o2.y + a0.z*o2.z + a0.w*o2.w;
            acc[0][3] += a0.x*o3.x + a0.y*o3.y + a0.z*o3.z + a0.w*o3.w;
            acc[1][0] += a1.x*o0.x + a1.y*o0.y + a1.z*o0.z + a1.w*o0.w;
            acc[1][1] += a1.x*o1.x + a1.y*o1.y + a1.z*o1.z + a1.w*o1.w;
            acc[1][2] += a1.x*o2.x + a1.y*o2.y + a1.z*o2.z + a1.w*o2.w;
            acc[1][3] += a1.x*o3.x + a1.y*o3.y + a1.z*o3.z + a1.w*o3.w;
          }
          if (cp == 0) {
            float4 tw = *(const float4*)&wTrk[twoff + kk];
            tacc[0] += tw.x*o0.x + tw.y*o0.y + tw.z*o0.z + tw.w*o0.w;
            tacc[1] += tw.x*o1.x + tw.y*o1.y + tw.z*o1.z + tw.w*o1.w;
            tacc[2] += tw.x*o2.x + tw.y*o2.y + tw.z*o2.z + tw.w*o2.w;
            tacc[3] += tw.x*o3.x + tw.y*o3.y + tw.z*o3.z + tw.w*o3.w;
          }
        }
      }
      if (cp == 0) {                               // th part of tracking K
        #pragma unroll
        for (int jf = 0; jf < 4; ++jf) {
          float4 tw = *(const float4*)&wTrk[1536 + q * 16 + jf * 4];
          #pragma unroll
          for (int bi = 0; bi < 4; ++bi) {
            float4 th = *(const float4*)&th2s[bg + bi * 32][q * 16 + jf * 4];
            tacc[bi] += th.x*tw.x + th.y*tw.y + th.z*tw.z + th.w*tw.w;
          }
        }
      }
      #pragma unroll
      for (int ci = 0; ci < 2; ++ci)
        #pragma unroll
        for (int bi = 0; bi < 4; ++bi)
          accS[q][cp * 2 + ci][bg + bi * 32] = acc[ci][bi];
      if (cp == 0) {
        #pragma unroll
        for (int bi = 0; bi < 4; ++bi) accT[q][bg + bi * 32] = tacc[bi];
      }
      __syncthreads();
      if (t < NB)
        p.tg[(size_t)w * NB + t] = accT[0][t] + accT[1][t] + accT[2][t] + accT[3][t];
    } else {
      // shift step: direct-global tracking, 16-way K-split
      const int s = t >> 5, bg2 = t & 31;
      float tc_[4] = {0.f, 0.f, 0.f, 0.f};
      if (s < 12) {
        #pragma unroll
        for (int bi = 0; bi < 4; ++bi) {
          int b = bg2 + bi * 32;
          const float* src = nullptr;
          int twoff = 0;
          if (s < 4) { int bx = bufs[b]; twoff = s * 128;
                       if (bx < LL) src = p.seq + ((size_t)b * LL + bx) * 1024 + s * 128; }
          else if (s < 8) { twoff = 512 + (s - 4) * 128;
                            src = p.stack + ((size_t)b * SROWS + sp1s[b]) * 1024 + (s - 4) * 128; }
          else            { twoff = 512 + (s - 4) * 128;
                            src = p.stack + ((size_t)b * SROWS + sp2s[b]) * 1024 + (s - 8) * 128; }
          if (src) {
            #pragma unroll 8
            for (int kf = 0; kf < 32; ++kf) {
              float4 v  = *(const float4*)(src + kf * 4);
              float4 tw = *(const float4*)&wTrk[twoff + kf * 4];
              tc_[bi] += v.x*tw.x + v.y*tw.y + v.z*tw.z + v.w*tw.w;
            }
          }
        }
      } else if (s == 12) {
        #pragma unroll
        for (int bi = 0; bi < 4; ++bi) {
          int b = bg2 + bi * 32;
          #pragma unroll 4
          for (int jf = 0; jf < 16; ++jf) {
            float4 tw = *(const float4*)&wTrk[1536 + jf * 4];
            float4 th = *(const float4*)&th2s[b][jf * 4];
            tc_[bi] += th.x*tw.x + th.y*tw.y + th.z*tw.z + th.w*tw.w;
          }
        }
      }
      if (s < 13) {
        #pragma unroll
        for (int bi = 0; bi < 4; ++bi) accT[s][bg2 + bi * 32] = tc_[bi];
      }
      __syncthreads();
      if (t < NB) {
        float sm = 0.f;
        #pragma unroll
        for (int si = 0; si < 13; ++si) sm += accT[si][t];
        p.tg[(size_t)w * NB + t] = sm;
      }
    }

    gsync(p.bm, ++gen, w);

    // ================= SEG 2 =================
    float clv = 0.f, crv = 0.f, bhv = 0.f, bcv = 0.f;
    const int bF = t & 127, nF = (t >> 7) & 1;
    if (t < 256) {
      clv = p.stack[((size_t)bF * SROWS + sp1s[bF]) * 1024 + 512 + n0 + nF];
      crv = p.stack[((size_t)bF * SROWS + sp2s[bF]) * 1024 + 512 + n0 + nF];
      int bx = bufs[bF];
      if (bx < LL) {
        bhv = p.seq[((size_t)bF * LL + bx) * 1024 + n0 + nF];
        bcv = p.seq[((size_t)bF * LL + bx) * 1024 + 512 + n0 + nF];
      }
    }
    // tracking state update: thread (bb, q) owns tc[16] in regs
    {
      #pragma unroll
      for (int jj = 0; jj < 16; ++jj) {
        int j = q * 16 + jj;
        float gi = p.tg[(size_t)j * NB + bb]         + tbsum[j];
        float gf = p.tg[(size_t)(64 + j) * NB + bb]  + tbsum[64 + j];
        float gg = p.tg[(size_t)(128 + j) * NB + bb] + tbsum[128 + j];
        float go = p.tg[(size_t)(192 + j) * NB + bb] + tbsum[192 + j];
        float c2 = sigm(gf) * tcr[jj] + sigm(gi) * tanh_f(gg);
        float h2 = sigm(go) * tanh_f(c2);
        th2s[bb][j] = h2;
        tcr[jj] = c2;
      }
    }
    __syncthreads();
    if (anyred) {
      const int r0s = q * 2, r1s = r0s + 1;        // gate q, cols n0 / n0+1
      float x0 = 0.f, x1 = 0.f;
      #pragma unroll 4
      for (int j4 = 0; j4 < 64; j4 += 4) {
        float4 xv = *(const float4*)&th2s[bb][j4];
        float4 wa = *(const float4*)&wX[r0s][j4];
        float4 wb = *(const float4*)&wX[r1s][j4];
        x0 += xv.x*wa.x + xv.y*wa.y + xv.z*wa.z + xv.w*wa.w;
        x1 += xv.x*wb.x + xv.y*wb.y + xv.z*wb.z + xv.w*wb.w;
      }
      preS[bb][r0s] = accS[0][r0s][bb] + accS[1][r0s][bb] + accS[2][r0s][bb]
                    + accS[3][r0s][bb] + x0 + biasS[r0s];
      preS[bb][r1s] = accS[0][r1s][bb] + accS[1][r1s][bb] + accS[2][r1s][bb]
                    + accS[3][r1s][bb] + x1 + biasS[r1s];
    }
    __syncthreads();
    if (t < 256) {
      float h, c;
      if (reds[bF]) {
        float iv = sigm(preS[bF][0 + nF]);
        float ov = sigm(preS[bF][2 + nF]);
        float fv = sigm(preS[bF][4 + nF]);
        float uv = tanh_f(preS[bF][6 + nF]);
        c = iv * uv + fv * (clv + crv);
        h = ov * tanh_f(c);
      } else { h = bhv; c = bcv; }
      float* sr = p.stack + ((size_t)bF * SROWS + step) * 1024 + n0 + nF;
      sr[0] = h;
      sr[512] = c;
      if (step == TT) p.out[(size_t)bF * 512 + n0 + nF] = h;
    }
    gsync(p.bm, ++gen, w);
  }
}

extern "C" void kernel_launch(void* const* d_in, const int* in_sizes, int n_in,
                              void* d_out, int out_size, void* d_ws, size_t ws_size,
                              hipStream_t stream) {
  Params p;
  p.seq   = (const float*)d_in[0];
  p.trans = (const int*)d_in[1];
  p.Wx[0] = (const float*)d_in[2];   // W_i
  p.Wx[1] = (const float*)d_in[4];   // W_o
  p.Wx[2] = (const float*)d_in[4];   // W_o  (ref bug: f-gate uses W_o)
  p.Wx[3] = (const float*)d_in[5];   // W_u
  p.Ul[0] = (const float*)d_in[6];  p.Ur[0] = (const float*)d_in[7];    // i
  p.Ul[1] = (const float*)d_in[10]; p.Ur[1] = (const float*)d_in[11];   // o
  p.Ul[2] = (const float*)d_in[8];  p.Ur[2] = (const float*)d_in[9];    // f
  p.Ul[3] = (const float*)d_in[12]; p.Ur[3] = (const float*)d_in[13];   // u
  p.bias[0] = (const float*)d_in[14];  // b_i
  p.bias[1] = (const float*)d_in[16];  // b_o
  p.bias[2] = (const float*)d_in[15];  // b_f
  p.bias[3] = (const float*)d_in[17];  // b_u
  p.tWih = (const float*)d_in[18];
  p.tWhh = (const float*)d_in[19];
  p.tbih = (const float*)d_in[20];
  p.tbhh = (const float*)d_in[21];
  p.th0  = (const float*)d_in[22];
  p.tc0  = (const float*)d_in[23];

  float* ws = (float*)d_ws;
  size_t off = 0;
  p.stack = ws + off; off += (size_t)NB * SROWS * 1024;  // 32 MB
  p.tg    = ws + off; off += (size_t)256 * NB;           // 128 KB
  unsigned* barmem = (unsigned*)(ws + off); off += 512;
  if (off * sizeof(float) > ws_size) return;
  p.bm  = barmem;
  p.out = (float*)d_out;

  hipMemsetAsync(barmem, 0, 512 * sizeof(unsigned), stream);

  void* args[] = { &p };
  hipError_t e = hipLaunchCooperativeKernel((void*)spinn_kernel, dim3(NWG), dim3(NTH),
                                            args, 0, stream);
  if (e != hipSuccess) {
    (void)hipGetLastError();
    spinn_kernel<<<dim3(NWG), dim3(NTH), 0, stream>>>(p);
  }
}